// Round 1
// baseline (86.750 us; speedup 1.0000x reference)
//
#include <hip/hip_runtime.h>

// HadamardAdapter: out = x + w[row][d&31], where
//   z[row][j]  = (1/64) * sum_m y[row][m] * (-1)^popc(j&m),  y[row][m] = sum_{d%32==m} x[row][d]
//   zbar[j]    = mean_rows z[row][j]
//   w[row][m]  = (1/64) * sum_{j<24} leaky(adapter[j])*(z[row][j]-zbar[j]) * (-1)^popc(j&m)
// Exploits H = Sylvester-Hadamard/64: orthogonal => (x@H.T)@H = x; rows j<32 of H
// depend only on d&31.

#define NROWS 8192
#define DDIM  4096
#define NK    24

// Reduce per-thread float4 partial sums (residues 4*(t&7)+{0..3}) into y[0..31].
// Requires 256 threads. Leaves result in y[]; ends with __syncthreads().
__device__ __forceinline__ void row_y_reduce(float4 acc, int t, int wave, int lane,
                                             float4 (*ypart)[8], float* y)
{
#pragma unroll
    for (int off = 8; off < 64; off <<= 1) {
        acc.x += __shfl_xor(acc.x, off);
        acc.y += __shfl_xor(acc.y, off);
        acc.z += __shfl_xor(acc.z, off);
        acc.w += __shfl_xor(acc.w, off);
    }
    if (lane < 8) ypart[wave][lane] = acc;
    __syncthreads();
    if (t < 32) {
        const int g = t >> 2, c = t & 3;
        float s = 0.f;
#pragma unroll
        for (int w = 0; w < 4; ++w) {
            const float* p = (const float*)&ypart[w][g];
            s += p[c];
        }
        y[t] = s;
    }
    __syncthreads();
}

// Pass 1: fold rows -> z_j, accumulate global zsum[24].
__global__ __launch_bounds__(256) void hada_k1(const float* __restrict__ x,
                                               float* __restrict__ zsum)
{
    __shared__ float4 ypart[4][8];
    __shared__ float y[32];
    const int t = threadIdx.x;
    const int wave = t >> 6, lane = t & 63;
    float zacc = 0.f;

    for (int i = 0; i < 4; ++i) {
        const int row = blockIdx.x * 4 + i;
        const float4* __restrict__ xr = (const float4*)(x + (size_t)row * DDIM);
        float4 acc = make_float4(0.f, 0.f, 0.f, 0.f);
#pragma unroll
        for (int j = 0; j < 4; ++j) {
            float4 v = xr[t + 256 * j];
            acc.x += v.x; acc.y += v.y; acc.z += v.z; acc.w += v.w;
        }
        row_y_reduce(acc, t, wave, lane, ypart, y);
        if (t < NK) {
            float zv = 0.f;
#pragma unroll
            for (int m = 0; m < 32; ++m)
                zv += (__popc(t & m) & 1) ? -y[m] : y[m];
            zacc += zv * (1.f / 64.f);
        }
        __syncthreads();   // protect y/ypart before next row overwrites
    }
    if (t < NK) atomicAdd(&zsum[t], zacc);
}

// Pass 2: recompute z for the row (x held in registers), build w[32], out = x + w[d&31].
__global__ __launch_bounds__(256) void hada_k2(const float* __restrict__ x,
                                               const float* __restrict__ adapter,
                                               const float* __restrict__ zsum,
                                               float* __restrict__ out)
{
    __shared__ float4 ypart[4][8];
    __shared__ float y[32];
    __shared__ float cz[NK];
    __shared__ float wsh[32];
    const int t = threadIdx.x;
    const int wave = t >> 6, lane = t & 63;
    const int row = blockIdx.x;

    const float4* __restrict__ xr = (const float4*)(x + (size_t)row * DDIM);
    float4 v0 = xr[t];
    float4 v1 = xr[t + 256];
    float4 v2 = xr[t + 512];
    float4 v3 = xr[t + 768];

    float4 acc;
    acc.x = (v0.x + v1.x) + (v2.x + v3.x);
    acc.y = (v0.y + v1.y) + (v2.y + v3.y);
    acc.z = (v0.z + v1.z) + (v2.z + v3.z);
    acc.w = (v0.w + v1.w) + (v2.w + v3.w);

    row_y_reduce(acc, t, wave, lane, ypart, y);

    if (t < NK) {
        float zv = 0.f;
#pragma unroll
        for (int m = 0; m < 32; ++m)
            zv += (__popc(t & m) & 1) ? -y[m] : y[m];
        zv *= (1.f / 64.f);
        const float a = adapter[t];
        const float s = (a > 0.f) ? a : 0.01f * a;          // leaky_relu, slope 0.01
        const float zbar = zsum[t] * (1.f / (float)NROWS);
        cz[t] = s * (zv - zbar);
    }
    __syncthreads();

    if (t < 32) {
        float wv = 0.f;
#pragma unroll
        for (int j = 0; j < NK; ++j)
            wv += (__popc(j & t) & 1) ? -cz[j] : cz[j];
        wsh[t] = wv * (1.f / 64.f);
    }
    __syncthreads();

    const int m0 = (t & 7) * 4;
    const float wx = wsh[m0], wy = wsh[m0 + 1], wz = wsh[m0 + 2], ww = wsh[m0 + 3];

    float4* __restrict__ orow = (float4*)(out + (size_t)row * DDIM);
    v0.x += wx; v0.y += wy; v0.z += wz; v0.w += ww;
    v1.x += wx; v1.y += wy; v1.z += wz; v1.w += ww;
    v2.x += wx; v2.y += wy; v2.z += wz; v2.w += ww;
    v3.x += wx; v3.y += wy; v3.z += wz; v3.w += ww;
    orow[t]       = v0;
    orow[t + 256] = v1;
    orow[t + 512] = v2;
    orow[t + 768] = v3;
}

extern "C" void kernel_launch(void* const* d_in, const int* in_sizes, int n_in,
                              void* d_out, int out_size, void* d_ws, size_t ws_size,
                              hipStream_t stream) {
    const float* x       = (const float*)d_in[0];   // (4,2048,4096) f32
    const float* adapter = (const float*)d_in[1];   // (24,) f32
    // d_in[2] = H: unused (structure exploited analytically)
    float* out  = (float*)d_out;
    float* zsum = (float*)d_ws;                     // 24 floats of scratch

    hipMemsetAsync(zsum, 0, NK * sizeof(float), stream);
    hipLaunchKernelGGL(hada_k1, dim3(NROWS / 4), dim3(256), 0, stream, x, zsum);
    hipLaunchKernelGGL(hada_k2, dim3(NROWS), dim3(256), 0, stream,
                       x, adapter, zsum, out);
}

// Round 2
// 84.959 us; speedup vs baseline: 1.0211x; 1.0211x over previous
//
#include <hip/hip_runtime.h>

// HadamardAdapter on MI355X — fully analytic form.
// H = Sylvester-Hadamard/64 is orthogonal => (x@H.T)@H = x, so
//   out[row,d] = x[row,d] + wloc[row][d&31] - wbar[d&31]
// where (sigma(j,m) = (-1)^popc(j&m)):
//   y[row][m]  = sum_{d: d&31==m} x[row,d]
//   z[row][j]  = (1/64) sum_m y[row][m] sigma(j,m)           (j < 24)
//   wloc[row][m] = (1/64) sum_j s_j z[row][j] sigma(j,m),  s_j = leaky_relu(adapter_j)
//   wbar[m]    = (1/64) sum_j s_j zbar_j sigma(j,m),  zbar = mean_rows z
// zbar is linear in the global 32-residue fold Y[m] = sum_{rows} y[row][m],
// so pass 1 is a pure streaming 32-bin reduction (no per-row work).

#define NROWS 8192
#define DDIM  4096
#define NK    24
#define K1_BLOCKS 2048
#define K1_THREADS 256

typedef float v4f __attribute__((ext_vector_type(4)));

// ---------------- Pass 1: global 32-residue fold, per-block partials ----------
__global__ __launch_bounds__(256) void hk_fold(const float* __restrict__ x,
                                               float* __restrict__ part)
{
    const int t = threadIdx.x;
    const int gtid = blockIdx.x * K1_THREADS + t;
    const v4f* __restrict__ xv = (const v4f*)x;
    v4f acc = (v4f)0.f;
    // NROWS*DDIM/4 = 8388608 float4s; stride 2048*256 = 524288 => 16 iters.
    // stride % 8 == 0 so each thread's residues m = 4*(t&7)+c are constant.
#pragma unroll
    for (int i = 0; i < 16; ++i)
        acc += xv[(size_t)i * (K1_BLOCKS * K1_THREADS) + gtid];

#pragma unroll
    for (int off = 8; off < 64; off <<= 1) {
        acc.x += __shfl_xor(acc.x, off);
        acc.y += __shfl_xor(acc.y, off);
        acc.z += __shfl_xor(acc.z, off);
        acc.w += __shfl_xor(acc.w, off);
    }
    __shared__ v4f yp[4][8];
    const int wave = t >> 6, lane = t & 63;
    if (lane < 8) yp[wave][lane] = acc;
    __syncthreads();
    if (t < 32) {
        const int g = t >> 2, c = t & 3;
        float s = 0.f;
#pragma unroll
        for (int w = 0; w < 4; ++w) s += yp[w][g][c];
        part[blockIdx.x * 32 + t] = s;   // plain store: no memset, no atomics
    }
}

// ---------------- Pass 1b: partials -> wbar[32] (single tiny block) ----------
__global__ __launch_bounds__(1024) void hk_wbar(const float* __restrict__ part,
                                                const float* __restrict__ adapter,
                                                float* __restrict__ wbar)
{
    __shared__ float Y[32];
    __shared__ float czb[NK];
    const int t = threadIdx.x;
    if (t < 32) Y[t] = 0.f;
    __syncthreads();
    const int m = t & 31;
    float s = 0.f;
    for (int b = t >> 5; b < K1_BLOCKS; b += 32)   // 64 iters, coalesced rows
        s += part[b * 32 + m];
    atomicAdd(&Y[m], s);                           // LDS atomic, 32 per address
    __syncthreads();
    if (t < NK) {
        float zb = 0.f;
#pragma unroll
        for (int mm = 0; mm < 32; ++mm)
            zb += (__popc(t & mm) & 1) ? -Y[mm] : Y[mm];
        zb *= (1.f / 64.f) / (float)NROWS;
        const float a = adapter[t];
        const float sc = (a > 0.f) ? a : 0.01f * a;   // leaky_relu slope 0.01
        czb[t] = sc * zb;
    }
    __syncthreads();
    if (t < 32) {
        float wv = 0.f;
#pragma unroll
        for (int j = 0; j < NK; ++j)
            wv += (__popc(j & t) & 1) ? -czb[j] : czb[j];
        wbar[t] = wv * (1.f / 64.f);
    }
}

// ---------------- Pass 2: per-row wloc, out = x + wloc - wbar ----------------
__global__ __launch_bounds__(256) void hk_apply(const float* __restrict__ x,
                                                const float* __restrict__ adapter,
                                                const float* __restrict__ wbar,
                                                float* __restrict__ out)
{
    __shared__ v4f yp[4][8];
    __shared__ float y[32];
    __shared__ float cz[NK];
    __shared__ float wsh[32];
    const int t = threadIdx.x;
    const int wave = t >> 6, lane = t & 63;
    const size_t base = (size_t)blockIdx.x * (DDIM / 4);
    const v4f* __restrict__ xr = (const v4f*)x + base;

    v4f v0 = xr[t], v1 = xr[t + 256], v2 = xr[t + 512], v3 = xr[t + 768];
    v4f acc = (v0 + v1) + (v2 + v3);

#pragma unroll
    for (int off = 8; off < 64; off <<= 1) {
        acc.x += __shfl_xor(acc.x, off);
        acc.y += __shfl_xor(acc.y, off);
        acc.z += __shfl_xor(acc.z, off);
        acc.w += __shfl_xor(acc.w, off);
    }
    if (lane < 8) yp[wave][lane] = acc;
    __syncthreads();
    if (t < 32) {
        const int g = t >> 2, c = t & 3;
        float s = 0.f;
#pragma unroll
        for (int w = 0; w < 4; ++w) s += yp[w][g][c];
        y[t] = s;
    }
    __syncthreads();
    if (t < NK) {
        float zv = 0.f;
#pragma unroll
        for (int mm = 0; mm < 32; ++mm)
            zv += (__popc(t & mm) & 1) ? -y[mm] : y[mm];
        zv *= (1.f / 64.f);
        const float a = adapter[t];
        const float sc = (a > 0.f) ? a : 0.01f * a;
        cz[t] = sc * zv;
    }
    __syncthreads();
    if (t < 32) {
        float wv = 0.f;
#pragma unroll
        for (int j = 0; j < NK; ++j)
            wv += (__popc(j & t) & 1) ? -cz[j] : cz[j];
        wsh[t] = wv * (1.f / 64.f) - wbar[t];
    }
    __syncthreads();

    const int m0 = (t & 7) << 2;
    v4f wv4; wv4.x = wsh[m0]; wv4.y = wsh[m0 + 1]; wv4.z = wsh[m0 + 2]; wv4.w = wsh[m0 + 3];

    v4f* __restrict__ orow = (v4f*)out + base;
    // Non-temporal: keep x resident in Infinity Cache (out never reused on-chip).
    __builtin_nontemporal_store(v0 + wv4, &orow[t]);
    __builtin_nontemporal_store(v1 + wv4, &orow[t + 256]);
    __builtin_nontemporal_store(v2 + wv4, &orow[t + 512]);
    __builtin_nontemporal_store(v3 + wv4, &orow[t + 768]);
}

extern "C" void kernel_launch(void* const* d_in, const int* in_sizes, int n_in,
                              void* d_out, int out_size, void* d_ws, size_t ws_size,
                              hipStream_t stream) {
    const float* x       = (const float*)d_in[0];   // (4,2048,4096) f32
    const float* adapter = (const float*)d_in[1];   // (24,) f32
    float* out  = (float*)d_out;
    float* part = (float*)d_ws;                     // [2048][32] partials
    float* wbar = part + K1_BLOCKS * 32;            // [32]

    hipLaunchKernelGGL(hk_fold,  dim3(K1_BLOCKS), dim3(K1_THREADS), 0, stream, x, part);
    hipLaunchKernelGGL(hk_wbar,  dim3(1),         dim3(1024),       0, stream, part, adapter, wbar);
    hipLaunchKernelGGL(hk_apply, dim3(NROWS),     dim3(256),        0, stream, x, adapter, wbar, out);
}